// Round 12
// baseline (347.547 us; speedup 1.0000x reference)
//
#include <hip/hip_runtime.h>
#include <hip/hip_bf16.h>

#define HW   6400
#define NB   2
#define CC   256
#define CIM  32
#define PP   9
#define P2   18
#define ROWS (NB*HW)        // 12800
#define NCH  32
#define JCH  (HW/NCH)       // 200
#define JH   (JCH/2)        // 100
#define NGRP (ROWS/64)      // 200
#define CAPR 256            // survivor slots per row (mean ~72, +8 sigma)

typedef float f4 __attribute__((ext_vector_type(4)));

// ws layout (float offsets)
#define OFF_QN   0
#define OFF_KN   (OFF_QN + ROWS*CIM)
#define OFF_V    (OFF_KN + ROWS*CIM)
#define OFF_OV   (OFF_V  + ROWS*CIM)
#define OFF_PV   (OFF_OV + ROWS*CIM)            // A: pvals [ROWS][NCH][9]
#define OFF_PI   (OFF_PV + ROWS*NCH*PP)         // A: pidx  (int)
#define OFF_W1T  (OFF_PI + ROWS*NCH*PP)         // [32][256]
#define OFF_W2T  (OFF_W1T + CIM*CC)             // [256][256]
#define OFF_BF   (OFF_W2T + CC*CC)              // [256]
#define OFF_WQT  (OFF_BF + CC)                  // [256][32]
#define OFF_WKT  (OFF_WQT + CC*CIM)
#define OFF_WVT  (OFF_WKT + CC*CIM)
#define OFF_TH   (OFF_WVT + CC*CIM)             // theta [ROWS]
#define OFF_SC   (OFF_TH + ROWS)                // survivor counts [ROWS] (int)
// SV (survivor pairs [ROWS][CAPR][2]) aliases the dead PV/PI region:
#define OFF_SV   OFF_PV                         // 12800*256*2 = 6.55M <= 7.37M ok
// total ~9.14M floats ~36.6MB

// ---------------- prep: fold BN/catt/back_w into GEMM weights; transpose Wq/Wk/Wv
__global__ void prep_kernel(const float* __restrict__ mlp_w, const float* __restrict__ mlp_b,
                            const float* __restrict__ mlp_g, const float* __restrict__ mlp_be,
                            const float* __restrict__ back_w, const float* __restrict__ catt,
                            const float* __restrict__ catt1,
                            const float* __restrict__ Wq, const float* __restrict__ Wk,
                            const float* __restrict__ Wv, float* __restrict__ ws) {
    const int blk = blockIdx.x, t = threadIdx.x;
    const float bnc = rsqrtf(1.0f + 1e-5f);
    if (blk < 32) {                       // W1fT[d][o]
        const int d = blk, o = t;
        const float g = mlp_g[o] * bnc;
        float acc = 0.f;
        for (int c = 0; c < CC; ++c)
            acc = fmaf(mlp_w[o*512 + c] * catt[c], back_w[c*CIM + d], acc);
        ws[OFF_W1T + d*CC + o] = g * acc;
    } else if (blk == 32) {               // W2fT[c][o] + biasf
        const int o = t;
        const float g = mlp_g[o] * bnc;
        for (int c = 0; c < CC; ++c)
            ws[OFF_W2T + c*CC + o] = g * mlp_w[o*512 + 256 + c] * catt1[c];
        ws[OFF_BF + o] = g * mlp_b[o] + mlp_be[o];
    } else {                              // WqT/WkT/WvT [c][d]
        const float* W = (blk == 33) ? Wq : (blk == 34) ? Wk : Wv;
        float* WT = ws + ((blk == 33) ? OFF_WQT : (blk == 34) ? OFF_WKT : OFF_WVT);
        for (int i = t; i < CC*CIM; i += 256) {
            const int c = i / CIM, d = i % CIM;
            WT[c*CIM + d] = W[d*CC + c];
        }
    }
}

// ---------------- qkv: q/k/v projections + l2norm of q,k  (verified, unchanged)
__global__ __launch_bounds__(256) void qkv_kernel(const float* __restrict__ feat,
                                                  const float* __restrict__ ws_r,
                                                  float* __restrict__ ws) {
    __shared__ float part[4][64][33];
    __shared__ float invA[64];
    const int bx = blockIdx.x;
    const int mat = bx % 3;               // 0=q,1=k,2=v
    const int ng  = bx / 3;
    const int n0  = ng * 64;
    const int b   = n0 / HW;              // uniform
    const int nsp0 = n0 % HW;
    const int tid = threadIdx.x;
    const int w = __builtin_amdgcn_readfirstlane(tid >> 6);
    const int lane = tid & 63;
    const float* WT = ws_r + (mat == 0 ? OFF_WQT : mat == 1 ? OFF_WKT : OFF_WVT);
    const float* fbase = feat + (size_t)b*CC*HW + nsp0 + lane;
    float acc[CIM];
#pragma unroll
    for (int d = 0; d < CIM; ++d) acc[d] = 0.f;
    const int c0 = w * 64;
    for (int cc = 0; cc < 64; ++cc) {
        const int c = c0 + cc;
        const float fv = fbase[(size_t)c * HW];
        const float* wt = WT + c*CIM;
#pragma unroll
        for (int d = 0; d < CIM; ++d) acc[d] = fmaf(fv, wt[d], acc[d]);
    }
#pragma unroll
    for (int d = 0; d < CIM; ++d) part[w][lane][d] = acc[d];
    __syncthreads();
    {
        const int n = tid >> 2, d0 = (tid & 3) * 8;
#pragma unroll
        for (int dd = 0; dd < 8; ++dd) {
            const int d = d0 + dd;
            part[0][n][d] = part[0][n][d] + part[1][n][d] + part[2][n][d] + part[3][n][d];
        }
    }
    __syncthreads();
    if (mat < 2) {
        if (tid < 64) {
            const int n = tid;
            float ss = 0.f;
#pragma unroll
            for (int d = 0; d < CIM; ++d) { const float x = part[0][n][d]; ss = fmaf(x, x, ss); }
            invA[n] = 1.0f / fmaxf(sqrtf(ss), 1e-12f);
        }
        __syncthreads();
    }
    float* outp = ws + (mat == 0 ? OFF_QN : mat == 1 ? OFF_KN : OFF_V);
    {
        const int n = tid >> 2, d0 = (tid & 3) * 8;
        const float scl = (mat < 2) ? invA[n] : 1.0f;
        const size_t r = (size_t)(n0 + n);
#pragma unroll
        for (int dd = 0; dd < 8; ++dd)
            outp[r*CIM + d0 + dd] = part[0][n][d0 + dd] * scl;
    }
}

// ---------------- A: subsample top9 (verified, unchanged)
__global__ __launch_bounds__(256) void attn_sample(const float* __restrict__ ws_r,
                                                   float* __restrict__ ws) {
    const int tid  = threadIdx.x;
    const int wid  = (blockIdx.x << 2) + (tid >> 6);
    const int lane = tid & 63;
    const int rg = __builtin_amdgcn_readfirstlane(wid >> 5);       // 0..199
    const int ch = __builtin_amdgcn_readfirstlane(wid & (NCH-1));  // 0..31
    const int r = rg*64 + lane;
    const int b = (rg*64) / HW;
    const float* qn = ws_r + OFF_QN + (size_t)r*CIM;
    float q[CIM];
    {   const f4* qv = (const f4*)qn;
        f4* q4 = (f4*)q;
#pragma unroll
        for (int h = 0; h < 8; ++h) q4[h] = qv[h];
    }
    const float* kbase = ws_r + OFF_KN + ((size_t)b*HW + ch*JCH)*CIM;
    const int jbase = ch*JCH;
    float tv[PP]; int ti[PP];
#pragma unroll
    for (int s = 0; s < PP; ++s) { tv[s] = -3.0e38f; ti[s] = 0; }
    for (int j = 0; j < JCH; j += 8) {          // 25 samples per chunk
        const float* kp = kbase + j*CIM;        // wave-uniform -> s_load
        float a0 = 0.f, a1 = 0.f, a2 = 0.f, a3 = 0.f;
#pragma unroll
        for (int d = 0; d < CIM; d += 4) {
            a0 = fmaf(q[d+0], kp[d+0], a0);
            a1 = fmaf(q[d+1], kp[d+1], a1);
            a2 = fmaf(q[d+2], kp[d+2], a2);
            a3 = fmaf(q[d+3], kp[d+3], a3);
        }
        const float wv = (a0 + a1) + (a2 + a3);
        if (wv > tv[8]) {
            tv[8] = wv; ti[8] = jbase + j;
#pragma unroll
            for (int s = 8; s > 0; --s) {
                const bool sw = tv[s] > tv[s-1];
                const float vA = tv[s-1], vB = tv[s];
                tv[s-1] = sw ? vB : vA;  tv[s] = sw ? vA : vB;
                const int iA = ti[s-1], iB = ti[s];
                ti[s-1] = sw ? iB : iA;  ti[s] = sw ? iA : iB;
            }
        }
    }
    float* pv = ws + OFF_PV + ((size_t)r*NCH + ch)*PP;
    int*   pi = (int*)(ws + OFF_PI) + ((size_t)r*NCH + ch)*PP;
#pragma unroll
    for (int s = 0; s < PP; ++s) { pv[s] = tv[s]; pi[s] = ti[s]; }
}

// ---------------- B: theta = s9 of the 800-point sample (verified, unchanged)
#define NSLOT 5
__global__ __launch_bounds__(256) void theta_kernel(const float* __restrict__ ws_r,
                                                    float* __restrict__ ws) {
    const int tid = threadIdx.x;
    const int w = tid >> 6, lane = tid & 63;
    const int r = blockIdx.x*4 + w;
    const float* pv = ws_r + OFF_PV + (size_t)r*NCH*PP;
    const int*   pi = (const int*)(ws_r + OFF_PI) + (size_t)r*NCH*PP;
    float cv[NSLOT]; int ci[NSLOT];
#pragma unroll
    for (int i = 0; i < NSLOT; ++i) {
        const int s = lane + 64*i;
        if (s < NCH*PP) { cv[i] = pv[s]; ci[i] = pi[s]; }
        else            { cv[i] = -3e38f; ci[i] = 0x7fffffff; }
    }
    float s9 = -3e38f;
#pragma unroll
    for (int rd = 0; rd < PP; ++rd) {
        float hv = cv[0]; int hi = ci[0]; int hs = 0;
#pragma unroll
        for (int i = 1; i < NSLOT; ++i)
            if (cv[i] > hv || (cv[i] == hv && ci[i] < hi)) { hv = cv[i]; hi = ci[i]; hs = i; }
        float bv = hv; int bi = hi;
#pragma unroll
        for (int off = 32; off >= 1; off >>= 1) {
            const float ov_ = __shfl_xor(bv, off);
            const int   oi_ = __shfl_xor(bi, off);
            if (ov_ > bv || (ov_ == bv && oi_ < bi)) { bv = ov_; bi = oi_; }
        }
        const bool won = (hv == bv && hi == bi);
#pragma unroll
        for (int i = 0; i < NSLOT; ++i)
            if (won && i == hs) cv[i] = -3e38f;
        s9 = bv;
    }
    if (lane == 0) {
        ws[OFF_TH + r] = s9;
        ((int*)(ws + OFF_SC))[r] = 0;
    }
}

// ---------------- C: full scan, 2-way ILP (two independent j-streams per iter)
// Two s_loads in flight per iteration hide L2 latency that R11's single
// serial chain exposed (267 cyc/step measured, only 85 VALU). Dot fma tree
// per stream is bit-identical to the verified kernel.
__global__ __launch_bounds__(256) void attn_filter(const float* __restrict__ ws_r,
                                                   float* __restrict__ ws) {
    const int tid  = threadIdx.x;
    const int wid  = (blockIdx.x << 2) + (tid >> 6);
    const int lane = tid & 63;
    const int rg = __builtin_amdgcn_readfirstlane(wid >> 5);
    const int ch = __builtin_amdgcn_readfirstlane(wid & (NCH-1));
    const int r = rg*64 + lane;
    const int b = (rg*64) / HW;
    const float* qn = ws_r + OFF_QN + (size_t)r*CIM;
    float q[CIM];
    {   const f4* qv = (const f4*)qn;
        f4* q4 = (f4*)q;
#pragma unroll
        for (int h = 0; h < 8; ++h) q4[h] = qv[h];
    }
    const float th = ws_r[OFF_TH + r];          // per-lane
    int* sc = (int*)(ws + OFF_SC);
    float* sv = ws + OFF_SV;
    const float* kbaseA = ws_r + OFF_KN + ((size_t)b*HW + ch*JCH)*CIM;
    const float* kbaseB = kbaseA + (size_t)JH*CIM;
    const int jbase = ch*JCH;
#pragma unroll 2
    for (int j = 0; j < JH; ++j) {
        const float* kpA = kbaseA + j*CIM;      // wave-uniform -> s_load
        const float* kpB = kbaseB + j*CIM;      // independent second stream
        float a0 = 0.f, a1 = 0.f, a2 = 0.f, a3 = 0.f;
        float b0 = 0.f, b1 = 0.f, b2 = 0.f, b3 = 0.f;
#pragma unroll
        for (int d = 0; d < CIM; d += 4) {
            a0 = fmaf(q[d+0], kpA[d+0], a0);
            a1 = fmaf(q[d+1], kpA[d+1], a1);
            a2 = fmaf(q[d+2], kpA[d+2], a2);
            a3 = fmaf(q[d+3], kpA[d+3], a3);
            b0 = fmaf(q[d+0], kpB[d+0], b0);
            b1 = fmaf(q[d+1], kpB[d+1], b1);
            b2 = fmaf(q[d+2], kpB[d+2], b2);
            b3 = fmaf(q[d+3], kpB[d+3], b3);
        }
        const float wvA = (a0 + a1) + (a2 + a3);
        const float wvB = (b0 + b1) + (b2 + b3);
        if (wvA >= th) {                         // >=: keeps ties at theta (exactness)
            const int slot = atomicAdd(&sc[r], 1);
            if (slot < CAPR) {
                float2 pr; pr.x = wvA; pr.y = __int_as_float(jbase + j);
                *(float2*)(sv + ((size_t)r*CAPR + slot)*2) = pr;
            }
        }
        if (wvB >= th) {
            const int slot = atomicAdd(&sc[r], 1);
            if (slot < CAPR) {
                float2 pr; pr.x = wvB; pr.y = __int_as_float(jbase + JH + j);
                *(float2*)(sv + ((size_t)r*CAPR + slot)*2) = pr;
            }
        }
    }
}

// ---------------- D: exact top9 of survivors + MLP + softmax + P.V (verified)
#define NS2 4    // CAPR/64
__global__ __launch_bounds__(256) void merge2_kernel(const float* __restrict__ ws_r,
                                                     const float* __restrict__ pm_w1,
                                                     const float* __restrict__ pm_w2,
                                                     const float* __restrict__ ad_w,
                                                     const float* __restrict__ ad_b,
                                                     float* __restrict__ ws) {
    __shared__ float pm1[P2*PP];
    __shared__ float pm2[PP*P2];
    const int tid = threadIdx.x;
    for (int i = tid; i < P2*PP; i += 256) pm1[i] = pm_w1[i];
    for (int i = tid; i < PP*P2; i += 256) pm2[i] = pm_w2[i];
    __syncthreads();
    const int w = tid >> 6, lane = tid & 63;
    const int r = blockIdx.x*4 + w;
    const int b = r / HW;
    const int cnt0 = ((const int*)(ws_r + OFF_SC))[r];
    const int cnl = cnt0 < CAPR ? cnt0 : CAPR;
    const float* svp = ws_r + OFF_SV + (size_t)r*CAPR*2;
    float cv[NS2]; int ci[NS2];
#pragma unroll
    for (int i = 0; i < NS2; ++i) {
        const int s = lane + 64*i;
        if (s < cnl) {
            const float2 pr = *(const float2*)(svp + (size_t)s*2);
            cv[i] = pr.x; ci[i] = __float_as_int(pr.y);
        } else { cv[i] = -3e38f; ci[i] = 0x7fffffff; }
    }
    float topv[PP]; int topi[PP];
#pragma unroll
    for (int rd = 0; rd < PP; ++rd) {
        float hv = cv[0]; int hi = ci[0]; int hs = 0;
#pragma unroll
        for (int i = 1; i < NS2; ++i)
            if (cv[i] > hv || (cv[i] == hv && ci[i] < hi)) { hv = cv[i]; hi = ci[i]; hs = i; }
        float bv = hv; int bi = hi;
#pragma unroll
        for (int off = 32; off >= 1; off >>= 1) {
            const float ov_ = __shfl_xor(bv, off);
            const int   oi_ = __shfl_xor(bi, off);
            if (ov_ > bv || (ov_ == bv && oi_ < bi)) { bv = ov_; bi = oi_; }
        }
        const bool won = (hv == bv && hi == bi);   // unique (indices unique)
#pragma unroll
        for (int i = 0; i < NS2; ++i)
            if (won && i == hs) cv[i] = -3e38f;
        topv[rd] = bv;
        topi[rd] = (bi >= 0 && bi < HW) ? bi : 0;  // defensive clamp
    }
    // per-row MLP (verified, unchanged)
    const float adw = ad_w[0], adb = ad_b[0];
    float xa[PP], pos[PP];
#pragma unroll
    for (int p = 0; p < PP; ++p) { xa[p] = fmaf(topv[p], adw, adb); pos[p] = fmaxf(xa[p], 0.f); }
    float hdn[P2];
#pragma unroll
    for (int qq = 0; qq < P2; ++qq) {
        float a = 0.f;
#pragma unroll
        for (int p = 0; p < PP; ++p) a = fmaf(pos[p], pm1[qq*PP + p], a);
        hdn[qq] = fmaxf(a, 0.f);
    }
    float msk[PP];
#pragma unroll
    for (int p = 0; p < PP; ++p) {
        float a = 0.f;
#pragma unroll
        for (int qq = 0; qq < P2; ++qq) a = fmaf(hdn[qq], pm2[p*P2 + qq], a);
        msk[p] = 1.0f / (1.0f + expf(-a));
    }
    float xm[PP], m = -3e38f;
#pragma unroll
    for (int p = 0; p < PP; ++p) { xm[p] = xa[p] > 0.f ? xa[p] : -100000.0f; m = fmaxf(m, xm[p]); }
    float e[PP], ssum = 0.f;
#pragma unroll
    for (int p = 0; p < PP; ++p) { e[p] = expf(xm[p] - m); ssum += e[p]; }
    float wf[PP];
#pragma unroll
    for (int p = 0; p < PP; ++p) wf[p] = (e[p] / ssum) * msk[p];
    const int d = lane & 31;
    const float* vb = ws_r + OFF_V + (size_t)b*HW*CIM;
    float acc = 0.f;
#pragma unroll
    for (int p = 0; p < PP; ++p) acc = fmaf(wf[p], vb[(size_t)topi[p]*CIM + d], acc);
    if (lane < 32) ws[OFF_OV + (size_t)r*CIM + d] = acc;
}

// ---------------- final fused 1x1 conv (288-dim) + BN + ReLU -> f32 out (verified)
__global__ __launch_bounds__(64) void fin_kernel(const float* __restrict__ feat,
                                                 const float* __restrict__ ws_r,
                                                 float* __restrict__ out) {
    __shared__ float ovt[64*33];
    const int bx = blockIdx.x;
    const int ng = bx % NGRP;
    const int og = bx / NGRP;             // 0..15
    const int n0 = ng*64;
    const int b  = n0 / HW;
    const int nsp0 = n0 % HW;
    const int lane = threadIdx.x;
    const float4* ovg = (const float4*)(ws_r + OFF_OV + (size_t)n0*CIM);
#pragma unroll
    for (int i = 0; i < 8; ++i) {
        const int f = lane + 64*i;
        const float4 vv = ovg[f];
        const int row = f >> 3, col = (f & 7) * 4;
        ovt[row*33 + col]     = vv.x;
        ovt[row*33 + col + 1] = vv.y;
        ovt[row*33 + col + 2] = vv.z;
        ovt[row*33 + col + 3] = vv.w;
    }
    __syncthreads();
    const int o0 = og * 16;
    float acc[16];
    const float* bfp = ws_r + OFF_BF;
#pragma unroll
    for (int oi = 0; oi < 16; ++oi) acc[oi] = bfp[o0 + oi];
    const float* w1t = ws_r + OFF_W1T;
#pragma unroll 4
    for (int dd = 0; dd < CIM; ++dd) {
        const float xv = ovt[lane*33 + dd];
        const float* wrow = w1t + dd*CC + o0;
#pragma unroll
        for (int oi = 0; oi < 16; ++oi) acc[oi] = fmaf(xv, wrow[oi], acc[oi]);
    }
    const float* w2t = ws_r + OFF_W2T;
    const float* fbase = feat + (size_t)b*CC*HW + nsp0 + lane;
#pragma unroll 4
    for (int c = 0; c < CC; ++c) {
        const float fv = fbase[(size_t)c * HW];
        const float* wrow = w2t + c*CC + o0;
#pragma unroll
        for (int oi = 0; oi < 16; ++oi) acc[oi] = fmaf(fv, wrow[oi], acc[oi]);
    }
    const size_t obase = (size_t)b*CC*HW + nsp0 + lane;
#pragma unroll
    for (int oi = 0; oi < 16; ++oi)
        out[obase + (size_t)(o0 + oi)*HW] = fmaxf(acc[oi], 0.f);
}

// ---------------- dsn head: 1x256 conv over x + BN + ReLU (verified)
__global__ __launch_bounds__(256) void dsn_kernel(const float* __restrict__ xout,
                                                  const float* __restrict__ dsn_w,
                                                  const float* __restrict__ dsn_b,
                                                  const float* __restrict__ dsn_g,
                                                  const float* __restrict__ dsn_be,
                                                  float* __restrict__ out) {
    const int t = blockIdx.x*256 + threadIdx.x;
    const int b = t / HW, nsp = t % HW;
    const float* xb = xout + (size_t)b*CC*HW + nsp;
    float acc = 0.f;
#pragma unroll 4
    for (int o = 0; o < CC; ++o)
        acc = fmaf(xb[(size_t)o*HW], dsn_w[o], acc);
    const float g = dsn_g[0] * rsqrtf(1.0f + 1e-5f);
    const float r0 = fmaxf(fmaf(g, acc + dsn_b[0], dsn_be[0]), 0.f);
    out[(size_t)NB*CC*HW + t] = r0;
}

extern "C" void kernel_launch(void* const* d_in, const int* in_sizes, int n_in,
                              void* d_out, int out_size, void* d_ws, size_t ws_size,
                              hipStream_t stream) {
    const float* feat  = (const float*)d_in[0];
    const float* Wq    = (const float*)d_in[1];
    const float* Wk    = (const float*)d_in[2];
    const float* Wv    = (const float*)d_in[3];
    const float* adw   = (const float*)d_in[4];
    const float* adb   = (const float*)d_in[5];
    const float* pm_w1 = (const float*)d_in[6];
    const float* pm_w2 = (const float*)d_in[7];
    const float* backw = (const float*)d_in[8];
    const float* catt  = (const float*)d_in[9];
    const float* catt1 = (const float*)d_in[10];
    const float* mlp_w = (const float*)d_in[11];
    const float* mlp_b = (const float*)d_in[12];
    const float* mlp_g = (const float*)d_in[13];
    const float* mlp_be= (const float*)d_in[14];
    const float* dsn_w = (const float*)d_in[15];
    const float* dsn_b = (const float*)d_in[16];
    const float* dsn_g = (const float*)d_in[17];
    const float* dsn_be= (const float*)d_in[18];
    float* ws = (float*)d_ws;
    float* out = (float*)d_out;

    prep_kernel<<<36, 256, 0, stream>>>(mlp_w, mlp_b, mlp_g, mlp_be, backw, catt, catt1,
                                        Wq, Wk, Wv, ws);
    qkv_kernel<<<NGRP*3, 256, 0, stream>>>(feat, ws, ws);
    attn_sample<<<(NGRP*NCH)/4, 256, 0, stream>>>(ws, ws);
    theta_kernel<<<ROWS/4, 256, 0, stream>>>(ws, ws);
    attn_filter<<<(NGRP*NCH)/4, 256, 0, stream>>>(ws, ws);
    merge2_kernel<<<ROWS/4, 256, 0, stream>>>(ws, pm_w1, pm_w2, adw, adb, ws);
    fin_kernel<<<NGRP*16, 64, 0, stream>>>(feat, ws, out);
    dsn_kernel<<<ROWS/256, 256, 0, stream>>>(out, dsn_w, dsn_b, dsn_g, dsn_be, out);
}

// Round 13
// 296.933 us; speedup vs baseline: 1.1705x; 1.1705x over previous
//
#include <hip/hip_runtime.h>
#include <hip/hip_bf16.h>

#define HW   6400
#define NB   2
#define CC   256
#define CIM  32
#define PP   9
#define P2   18
#define ROWS (NB*HW)        // 12800
#define NCH  32             // sample/theta chunking (verified layout)
#define JCH  (HW/NCH)       // 200
#define NCHF 64             // filter chunking (TLP: 12800 waves)
#define JCHF (HW/NCHF)      // 100
#define NGRP (ROWS/64)      // 200
#define CAPR 256            // survivor slots per row (mean ~72, +8 sigma)

typedef float f4 __attribute__((ext_vector_type(4)));

// ws layout (float offsets)
#define OFF_QN   0
#define OFF_KN   (OFF_QN + ROWS*CIM)
#define OFF_V    (OFF_KN + ROWS*CIM)
#define OFF_OV   (OFF_V  + ROWS*CIM)
#define OFF_PV   (OFF_OV + ROWS*CIM)            // A: pvals [ROWS][NCH][9]
#define OFF_PI   (OFF_PV + ROWS*NCH*PP)         // A: pidx  (int)
#define OFF_W1T  (OFF_PI + ROWS*NCH*PP)         // [32][256]
#define OFF_W2T  (OFF_W1T + CIM*CC)             // [256][256]
#define OFF_BF   (OFF_W2T + CC*CC)              // [256]
#define OFF_WQT  (OFF_BF + CC)                  // [256][32]
#define OFF_WKT  (OFF_WQT + CC*CIM)
#define OFF_WVT  (OFF_WKT + CC*CIM)
#define OFF_TH   (OFF_WVT + CC*CIM)             // theta [ROWS]
#define OFF_SC   (OFF_TH + ROWS)                // survivor counts [ROWS] (int)
// SV (survivor pairs [ROWS][CAPR][2]) aliases the dead PV/PI region:
#define OFF_SV   OFF_PV                         // 12800*256*2 = 6.55M <= 7.37M ok
// total ~9.14M floats ~36.6MB

// ---------------- prep: fold BN/catt/back_w into GEMM weights; transpose Wq/Wk/Wv
__global__ void prep_kernel(const float* __restrict__ mlp_w, const float* __restrict__ mlp_b,
                            const float* __restrict__ mlp_g, const float* __restrict__ mlp_be,
                            const float* __restrict__ back_w, const float* __restrict__ catt,
                            const float* __restrict__ catt1,
                            const float* __restrict__ Wq, const float* __restrict__ Wk,
                            const float* __restrict__ Wv, float* __restrict__ ws) {
    const int blk = blockIdx.x, t = threadIdx.x;
    const float bnc = rsqrtf(1.0f + 1e-5f);
    if (blk < 32) {                       // W1fT[d][o]
        const int d = blk, o = t;
        const float g = mlp_g[o] * bnc;
        float acc = 0.f;
        for (int c = 0; c < CC; ++c)
            acc = fmaf(mlp_w[o*512 + c] * catt[c], back_w[c*CIM + d], acc);
        ws[OFF_W1T + d*CC + o] = g * acc;
    } else if (blk == 32) {               // W2fT[c][o] + biasf
        const int o = t;
        const float g = mlp_g[o] * bnc;
        for (int c = 0; c < CC; ++c)
            ws[OFF_W2T + c*CC + o] = g * mlp_w[o*512 + 256 + c] * catt1[c];
        ws[OFF_BF + o] = g * mlp_b[o] + mlp_be[o];
    } else {                              // WqT/WkT/WvT [c][d]
        const float* W = (blk == 33) ? Wq : (blk == 34) ? Wk : Wv;
        float* WT = ws + ((blk == 33) ? OFF_WQT : (blk == 34) ? OFF_WKT : OFF_WVT);
        for (int i = t; i < CC*CIM; i += 256) {
            const int c = i / CIM, d = i % CIM;
            WT[c*CIM + d] = W[d*CC + c];
        }
    }
}

// ---------------- qkv: q/k/v projections + l2norm of q,k  (verified, unchanged)
__global__ __launch_bounds__(256) void qkv_kernel(const float* __restrict__ feat,
                                                  const float* __restrict__ ws_r,
                                                  float* __restrict__ ws) {
    __shared__ float part[4][64][33];
    __shared__ float invA[64];
    const int bx = blockIdx.x;
    const int mat = bx % 3;               // 0=q,1=k,2=v
    const int ng  = bx / 3;
    const int n0  = ng * 64;
    const int b   = n0 / HW;              // uniform
    const int nsp0 = n0 % HW;
    const int tid = threadIdx.x;
    const int w = __builtin_amdgcn_readfirstlane(tid >> 6);
    const int lane = tid & 63;
    const float* WT = ws_r + (mat == 0 ? OFF_WQT : mat == 1 ? OFF_WKT : OFF_WVT);
    const float* fbase = feat + (size_t)b*CC*HW + nsp0 + lane;
    float acc[CIM];
#pragma unroll
    for (int d = 0; d < CIM; ++d) acc[d] = 0.f;
    const int c0 = w * 64;
    for (int cc = 0; cc < 64; ++cc) {
        const int c = c0 + cc;
        const float fv = fbase[(size_t)c * HW];
        const float* wt = WT + c*CIM;
#pragma unroll
        for (int d = 0; d < CIM; ++d) acc[d] = fmaf(fv, wt[d], acc[d]);
    }
#pragma unroll
    for (int d = 0; d < CIM; ++d) part[w][lane][d] = acc[d];
    __syncthreads();
    {
        const int n = tid >> 2, d0 = (tid & 3) * 8;
#pragma unroll
        for (int dd = 0; dd < 8; ++dd) {
            const int d = d0 + dd;
            part[0][n][d] = part[0][n][d] + part[1][n][d] + part[2][n][d] + part[3][n][d];
        }
    }
    __syncthreads();
    if (mat < 2) {
        if (tid < 64) {
            const int n = tid;
            float ss = 0.f;
#pragma unroll
            for (int d = 0; d < CIM; ++d) { const float x = part[0][n][d]; ss = fmaf(x, x, ss); }
            invA[n] = 1.0f / fmaxf(sqrtf(ss), 1e-12f);
        }
        __syncthreads();
    }
    float* outp = ws + (mat == 0 ? OFF_QN : mat == 1 ? OFF_KN : OFF_V);
    {
        const int n = tid >> 2, d0 = (tid & 3) * 8;
        const float scl = (mat < 2) ? invA[n] : 1.0f;
        const size_t r = (size_t)(n0 + n);
#pragma unroll
        for (int dd = 0; dd < 8; ++dd)
            outp[r*CIM + d0 + dd] = part[0][n][d0 + dd] * scl;
    }
}

// ---------------- A: subsample top9 (verified, unchanged)
__global__ __launch_bounds__(256) void attn_sample(const float* __restrict__ ws_r,
                                                   float* __restrict__ ws) {
    const int tid  = threadIdx.x;
    const int wid  = (blockIdx.x << 2) + (tid >> 6);
    const int lane = tid & 63;
    const int rg = __builtin_amdgcn_readfirstlane(wid >> 5);       // 0..199
    const int ch = __builtin_amdgcn_readfirstlane(wid & (NCH-1));  // 0..31
    const int r = rg*64 + lane;
    const int b = (rg*64) / HW;
    const float* qn = ws_r + OFF_QN + (size_t)r*CIM;
    float q[CIM];
    {   const f4* qv = (const f4*)qn;
        f4* q4 = (f4*)q;
#pragma unroll
        for (int h = 0; h < 8; ++h) q4[h] = qv[h];
    }
    const float* kbase = ws_r + OFF_KN + ((size_t)b*HW + ch*JCH)*CIM;
    const int jbase = ch*JCH;
    float tv[PP]; int ti[PP];
#pragma unroll
    for (int s = 0; s < PP; ++s) { tv[s] = -3.0e38f; ti[s] = 0; }
    for (int j = 0; j < JCH; j += 8) {          // 25 samples per chunk
        const float* kp = kbase + j*CIM;        // wave-uniform -> s_load
        float a0 = 0.f, a1 = 0.f, a2 = 0.f, a3 = 0.f;
#pragma unroll
        for (int d = 0; d < CIM; d += 4) {
            a0 = fmaf(q[d+0], kp[d+0], a0);
            a1 = fmaf(q[d+1], kp[d+1], a1);
            a2 = fmaf(q[d+2], kp[d+2], a2);
            a3 = fmaf(q[d+3], kp[d+3], a3);
        }
        const float wv = (a0 + a1) + (a2 + a3);
        if (wv > tv[8]) {
            tv[8] = wv; ti[8] = jbase + j;
#pragma unroll
            for (int s = 8; s > 0; --s) {
                const bool sw = tv[s] > tv[s-1];
                const float vA = tv[s-1], vB = tv[s];
                tv[s-1] = sw ? vB : vA;  tv[s] = sw ? vA : vB;
                const int iA = ti[s-1], iB = ti[s];
                ti[s-1] = sw ? iB : iA;  ti[s] = sw ? iA : iB;
            }
        }
    }
    float* pv = ws + OFF_PV + ((size_t)r*NCH + ch)*PP;
    int*   pi = (int*)(ws + OFF_PI) + ((size_t)r*NCH + ch)*PP;
#pragma unroll
    for (int s = 0; s < PP; ++s) { pv[s] = tv[s]; pi[s] = ti[s]; }
}

// ---------------- B: theta = s9 of the 800-point sample (verified, unchanged)
#define NSLOT 5
__global__ __launch_bounds__(256) void theta_kernel(const float* __restrict__ ws_r,
                                                    float* __restrict__ ws) {
    const int tid = threadIdx.x;
    const int w = tid >> 6, lane = tid & 63;
    const int r = blockIdx.x*4 + w;
    const float* pv = ws_r + OFF_PV + (size_t)r*NCH*PP;
    const int*   pi = (const int*)(ws_r + OFF_PI) + (size_t)r*NCH*PP;
    float cv[NSLOT]; int ci[NSLOT];
#pragma unroll
    for (int i = 0; i < NSLOT; ++i) {
        const int s = lane + 64*i;
        if (s < NCH*PP) { cv[i] = pv[s]; ci[i] = pi[s]; }
        else            { cv[i] = -3e38f; ci[i] = 0x7fffffff; }
    }
    float s9 = -3e38f;
#pragma unroll
    for (int rd = 0; rd < PP; ++rd) {
        float hv = cv[0]; int hi = ci[0]; int hs = 0;
#pragma unroll
        for (int i = 1; i < NSLOT; ++i)
            if (cv[i] > hv || (cv[i] == hv && ci[i] < hi)) { hv = cv[i]; hi = ci[i]; hs = i; }
        float bv = hv; int bi = hi;
#pragma unroll
        for (int off = 32; off >= 1; off >>= 1) {
            const float ov_ = __shfl_xor(bv, off);
            const int   oi_ = __shfl_xor(bi, off);
            if (ov_ > bv || (ov_ == bv && oi_ < bi)) { bv = ov_; bi = oi_; }
        }
        const bool won = (hv == bv && hi == bi);
#pragma unroll
        for (int i = 0; i < NSLOT; ++i)
            if (won && i == hs) cv[i] = -3e38f;
        s9 = bv;
    }
    if (lane == 0) {
        ws[OFF_TH + r] = s9;
        ((int*)(ws + OFF_SC))[r] = 0;
    }
}

// ---------------- C: full scan, single-stream (verified R11 body), NCHF=64 for 2x TLP
__global__ __launch_bounds__(256) void attn_filter(const float* __restrict__ ws_r,
                                                   float* __restrict__ ws) {
    const int tid  = threadIdx.x;
    const int wid  = (blockIdx.x << 2) + (tid >> 6);   // 0..12799
    const int lane = tid & 63;
    const int rg = __builtin_amdgcn_readfirstlane(wid >> 6);        // 0..199
    const int ch = __builtin_amdgcn_readfirstlane(wid & (NCHF-1));  // 0..63
    const int r = rg*64 + lane;
    const int b = (rg*64) / HW;
    const float* qn = ws_r + OFF_QN + (size_t)r*CIM;
    float q[CIM];
    {   const f4* qv = (const f4*)qn;
        f4* q4 = (f4*)q;
#pragma unroll
        for (int h = 0; h < 8; ++h) q4[h] = qv[h];
    }
    const float th = ws_r[OFF_TH + r];          // per-lane, hoisted
    int* sc = (int*)(ws + OFF_SC);
    float* sv = ws + OFF_SV;
    const float* kbase = ws_r + OFF_KN + ((size_t)b*HW + ch*JCHF)*CIM;
    const int jbase = ch*JCHF;
#pragma unroll 2
    for (int j = 0; j < JCHF; ++j) {
        const float* kp = kbase + j*CIM;        // wave-uniform -> s_load
        float a0 = 0.f, a1 = 0.f, a2 = 0.f, a3 = 0.f;
#pragma unroll
        for (int d = 0; d < CIM; d += 4) {
            a0 = fmaf(q[d+0], kp[d+0], a0);
            a1 = fmaf(q[d+1], kp[d+1], a1);
            a2 = fmaf(q[d+2], kp[d+2], a2);
            a3 = fmaf(q[d+3], kp[d+3], a3);
        }
        const float wv = (a0 + a1) + (a2 + a3);
        if (wv >= th) {                          // >=: keeps ties at theta (exactness)
            const int slot = atomicAdd(&sc[r], 1);
            if (slot < CAPR) {                   // clamp: memory-safe
                float2 pr;
                pr.x = wv;
                pr.y = __int_as_float(jbase + j);
                *(float2*)(sv + ((size_t)r*CAPR + slot)*2) = pr;
            }
        }
    }
}

// ---------------- D: exact top9 of survivors + MLP + softmax + P.V (verified)
#define NS2 4    // CAPR/64
__global__ __launch_bounds__(256) void merge2_kernel(const float* __restrict__ ws_r,
                                                     const float* __restrict__ pm_w1,
                                                     const float* __restrict__ pm_w2,
                                                     const float* __restrict__ ad_w,
                                                     const float* __restrict__ ad_b,
                                                     float* __restrict__ ws) {
    __shared__ float pm1[P2*PP];
    __shared__ float pm2[PP*P2];
    const int tid = threadIdx.x;
    for (int i = tid; i < P2*PP; i += 256) pm1[i] = pm_w1[i];
    for (int i = tid; i < PP*P2; i += 256) pm2[i] = pm_w2[i];
    __syncthreads();
    const int w = tid >> 6, lane = tid & 63;
    const int r = blockIdx.x*4 + w;
    const int b = r / HW;
    const int cnt0 = ((const int*)(ws_r + OFF_SC))[r];
    const int cnl = cnt0 < CAPR ? cnt0 : CAPR;
    const float* svp = ws_r + OFF_SV + (size_t)r*CAPR*2;
    float cv[NS2]; int ci[NS2];
#pragma unroll
    for (int i = 0; i < NS2; ++i) {
        const int s = lane + 64*i;
        if (s < cnl) {
            const float2 pr = *(const float2*)(svp + (size_t)s*2);
            cv[i] = pr.x; ci[i] = __float_as_int(pr.y);
        } else { cv[i] = -3e38f; ci[i] = 0x7fffffff; }
    }
    float topv[PP]; int topi[PP];
#pragma unroll
    for (int rd = 0; rd < PP; ++rd) {
        float hv = cv[0]; int hi = ci[0]; int hs = 0;
#pragma unroll
        for (int i = 1; i < NS2; ++i)
            if (cv[i] > hv || (cv[i] == hv && ci[i] < hi)) { hv = cv[i]; hi = ci[i]; hs = i; }
        float bv = hv; int bi = hi;
#pragma unroll
        for (int off = 32; off >= 1; off >>= 1) {
            const float ov_ = __shfl_xor(bv, off);
            const int   oi_ = __shfl_xor(bi, off);
            if (ov_ > bv || (ov_ == bv && oi_ < bi)) { bv = ov_; bi = oi_; }
        }
        const bool won = (hv == bv && hi == bi);   // unique (indices unique)
#pragma unroll
        for (int i = 0; i < NS2; ++i)
            if (won && i == hs) cv[i] = -3e38f;
        topv[rd] = bv;
        topi[rd] = (bi >= 0 && bi < HW) ? bi : 0;  // defensive clamp
    }
    // per-row MLP (verified, unchanged)
    const float adw = ad_w[0], adb = ad_b[0];
    float xa[PP], pos[PP];
#pragma unroll
    for (int p = 0; p < PP; ++p) { xa[p] = fmaf(topv[p], adw, adb); pos[p] = fmaxf(xa[p], 0.f); }
    float hdn[P2];
#pragma unroll
    for (int qq = 0; qq < P2; ++qq) {
        float a = 0.f;
#pragma unroll
        for (int p = 0; p < PP; ++p) a = fmaf(pos[p], pm1[qq*PP + p], a);
        hdn[qq] = fmaxf(a, 0.f);
    }
    float msk[PP];
#pragma unroll
    for (int p = 0; p < PP; ++p) {
        float a = 0.f;
#pragma unroll
        for (int qq = 0; qq < P2; ++qq) a = fmaf(hdn[qq], pm2[p*P2 + qq], a);
        msk[p] = 1.0f / (1.0f + expf(-a));
    }
    float xm[PP], m = -3e38f;
#pragma unroll
    for (int p = 0; p < PP; ++p) { xm[p] = xa[p] > 0.f ? xa[p] : -100000.0f; m = fmaxf(m, xm[p]); }
    float e[PP], ssum = 0.f;
#pragma unroll
    for (int p = 0; p < PP; ++p) { e[p] = expf(xm[p] - m); ssum += e[p]; }
    float wf[PP];
#pragma unroll
    for (int p = 0; p < PP; ++p) wf[p] = (e[p] / ssum) * msk[p];
    const int d = lane & 31;
    const float* vb = ws_r + OFF_V + (size_t)b*HW*CIM;
    float acc = 0.f;
#pragma unroll
    for (int p = 0; p < PP; ++p) acc = fmaf(wf[p], vb[(size_t)topi[p]*CIM + d], acc);
    if (lane < 32) ws[OFF_OV + (size_t)r*CIM + d] = acc;
}

// ---------------- final fused 1x1 conv (288-dim) + BN + ReLU -> f32 out (verified)
__global__ __launch_bounds__(64) void fin_kernel(const float* __restrict__ feat,
                                                 const float* __restrict__ ws_r,
                                                 float* __restrict__ out) {
    __shared__ float ovt[64*33];
    const int bx = blockIdx.x;
    const int ng = bx % NGRP;
    const int og = bx / NGRP;             // 0..15
    const int n0 = ng*64;
    const int b  = n0 / HW;
    const int nsp0 = n0 % HW;
    const int lane = threadIdx.x;
    const float4* ovg = (const float4*)(ws_r + OFF_OV + (size_t)n0*CIM);
#pragma unroll
    for (int i = 0; i < 8; ++i) {
        const int f = lane + 64*i;
        const float4 vv = ovg[f];
        const int row = f >> 3, col = (f & 7) * 4;
        ovt[row*33 + col]     = vv.x;
        ovt[row*33 + col + 1] = vv.y;
        ovt[row*33 + col + 2] = vv.z;
        ovt[row*33 + col + 3] = vv.w;
    }
    __syncthreads();
    const int o0 = og * 16;
    float acc[16];
    const float* bfp = ws_r + OFF_BF;
#pragma unroll
    for (int oi = 0; oi < 16; ++oi) acc[oi] = bfp[o0 + oi];
    const float* w1t = ws_r + OFF_W1T;
#pragma unroll 4
    for (int dd = 0; dd < CIM; ++dd) {
        const float xv = ovt[lane*33 + dd];
        const float* wrow = w1t + dd*CC + o0;
#pragma unroll
        for (int oi = 0; oi < 16; ++oi) acc[oi] = fmaf(xv, wrow[oi], acc[oi]);
    }
    const float* w2t = ws_r + OFF_W2T;
    const float* fbase = feat + (size_t)b*CC*HW + nsp0 + lane;
#pragma unroll 4
    for (int c = 0; c < CC; ++c) {
        const float fv = fbase[(size_t)c * HW];
        const float* wrow = w2t + c*CC + o0;
#pragma unroll
        for (int oi = 0; oi < 16; ++oi) acc[oi] = fmaf(fv, wrow[oi], acc[oi]);
    }
    const size_t obase = (size_t)b*CC*HW + nsp0 + lane;
#pragma unroll
    for (int oi = 0; oi < 16; ++oi)
        out[obase + (size_t)(o0 + oi)*HW] = fmaxf(acc[oi], 0.f);
}

// ---------------- dsn head: 1x256 conv over x + BN + ReLU (verified)
__global__ __launch_bounds__(256) void dsn_kernel(const float* __restrict__ xout,
                                                  const float* __restrict__ dsn_w,
                                                  const float* __restrict__ dsn_b,
                                                  const float* __restrict__ dsn_g,
                                                  const float* __restrict__ dsn_be,
                                                  float* __restrict__ out) {
    const int t = blockIdx.x*256 + threadIdx.x;
    const int b = t / HW, nsp = t % HW;
    const float* xb = xout + (size_t)b*CC*HW + nsp;
    float acc = 0.f;
#pragma unroll 4
    for (int o = 0; o < CC; ++o)
        acc = fmaf(xb[(size_t)o*HW], dsn_w[o], acc);
    const float g = dsn_g[0] * rsqrtf(1.0f + 1e-5f);
    const float r0 = fmaxf(fmaf(g, acc + dsn_b[0], dsn_be[0]), 0.f);
    out[(size_t)NB*CC*HW + t] = r0;
}

extern "C" void kernel_launch(void* const* d_in, const int* in_sizes, int n_in,
                              void* d_out, int out_size, void* d_ws, size_t ws_size,
                              hipStream_t stream) {
    const float* feat  = (const float*)d_in[0];
    const float* Wq    = (const float*)d_in[1];
    const float* Wk    = (const float*)d_in[2];
    const float* Wv    = (const float*)d_in[3];
    const float* adw   = (const float*)d_in[4];
    const float* adb   = (const float*)d_in[5];
    const float* pm_w1 = (const float*)d_in[6];
    const float* pm_w2 = (const float*)d_in[7];
    const float* backw = (const float*)d_in[8];
    const float* catt  = (const float*)d_in[9];
    const float* catt1 = (const float*)d_in[10];
    const float* mlp_w = (const float*)d_in[11];
    const float* mlp_b = (const float*)d_in[12];
    const float* mlp_g = (const float*)d_in[13];
    const float* mlp_be= (const float*)d_in[14];
    const float* dsn_w = (const float*)d_in[15];
    const float* dsn_b = (const float*)d_in[16];
    const float* dsn_g = (const float*)d_in[17];
    const float* dsn_be= (const float*)d_in[18];
    float* ws = (float*)d_ws;
    float* out = (float*)d_out;

    prep_kernel<<<36, 256, 0, stream>>>(mlp_w, mlp_b, mlp_g, mlp_be, backw, catt, catt1,
                                        Wq, Wk, Wv, ws);
    qkv_kernel<<<NGRP*3, 256, 0, stream>>>(feat, ws, ws);
    attn_sample<<<(NGRP*NCH)/4, 256, 0, stream>>>(ws, ws);
    theta_kernel<<<ROWS/4, 256, 0, stream>>>(ws, ws);
    attn_filter<<<(NGRP*NCHF)/4, 256, 0, stream>>>(ws, ws);
    merge2_kernel<<<ROWS/4, 256, 0, stream>>>(ws, pm_w1, pm_w2, adw, adb, ws);
    fin_kernel<<<NGRP*16, 64, 0, stream>>>(feat, ws, out);
    dsn_kernel<<<ROWS/256, 256, 0, stream>>>(out, dsn_w, dsn_b, dsn_g, dsn_be, out);
}